// Round 1
// baseline (363.435 us; speedup 1.0000x reference)
//
#include <hip/hip_runtime.h>

// IntensityTransformation: out_k[b,c,h,w] = tf_k[b,c, round(255*img[b,c,h,w])]
// B=8, C=3, H=W=1024, LUT=256. Memory-bound LUT gather.
//
// Layout: one block per (plane, chunk); plane = b*C+c in [0,24).
// Each block stages the plane's three 256-float LUTs into LDS (3 KB),
// then each thread processes one float4 (4 pixels): 16 B read, 48 B written.

#define PLANES 24          // B*C
#define PLANE_PIX (1024 * 1024)
#define VEC4_PER_PLANE (PLANE_PIX / 4)      // 262144
#define BLOCK 256
#define BLOCKS_PER_PLANE (VEC4_PER_PLANE / BLOCK)   // 1024
#define TOTAL_VEC4 (PLANES * VEC4_PER_PLANE)        // 6291456

__global__ __launch_bounds__(BLOCK) void intensity_lut_kernel(
    const float4* __restrict__ img,
    const float*  __restrict__ tf1,
    const float*  __restrict__ tf2,
    const float*  __restrict__ tf3,
    float4* __restrict__ out)
{
    __shared__ float l1[256];
    __shared__ float l2[256];
    __shared__ float l3[256];

    const int plane = blockIdx.y;      // 0..23
    const int t = threadIdx.x;         // 0..255

    // Stage this plane's LUTs into LDS: 256 threads, 256 entries each table.
    l1[t] = tf1[plane * 256 + t];
    l2[t] = tf2[plane * 256 + t];
    l3[t] = tf3[plane * 256 + t];
    __syncthreads();

    const long long i = (long long)plane * VEC4_PER_PLANE
                      + (long long)blockIdx.x * BLOCK + t;

    float4 v = img[i];

    // jnp.round is round-half-to-even; __float2int_rn matches.
    int i0 = __float2int_rn(255.0f * v.x);
    int i1 = __float2int_rn(255.0f * v.y);
    int i2 = __float2int_rn(255.0f * v.z);
    int i3 = __float2int_rn(255.0f * v.w);
    i0 = min(max(i0, 0), 255);
    i1 = min(max(i1, 0), 255);
    i2 = min(max(i2, 0), 255);
    i3 = min(max(i3, 0), 255);

    float4 o1 = make_float4(l1[i0], l1[i1], l1[i2], l1[i3]);
    float4 o2 = make_float4(l2[i0], l2[i1], l2[i2], l2[i3]);
    float4 o3 = make_float4(l3[i0], l3[i1], l3[i2], l3[i3]);

    out[i]                   = o1;   // tf1 output block
    out[i + TOTAL_VEC4]      = o2;   // tf2 output block
    out[i + 2LL * TOTAL_VEC4] = o3;  // tf3 output block
}

extern "C" void kernel_launch(void* const* d_in, const int* in_sizes, int n_in,
                              void* d_out, int out_size, void* d_ws, size_t ws_size,
                              hipStream_t stream) {
    const float4* img = (const float4*)d_in[0];
    const float*  tf1 = (const float*)d_in[1];
    const float*  tf2 = (const float*)d_in[2];
    const float*  tf3 = (const float*)d_in[3];
    float4* out = (float4*)d_out;

    dim3 grid(BLOCKS_PER_PLANE, PLANES);
    dim3 block(BLOCK);
    intensity_lut_kernel<<<grid, block, 0, stream>>>(img, tf1, tf2, tf3, out);
}